// Round 12
// baseline (349.909 us; speedup 1.0000x reference)
//
#include <hip/hip_runtime.h>
#include <cstddef>
#include <cstdint>

#define TT 2048
#define HH 16
#define EPSV 1.1920929e-07f
#define QSCALE 0.08838834764831845f   // 1/sqrt(128)
#define LOG2E 1.4426950408889634f
#define THRL 11.0f                    // defer-rescale threshold (log2 units)

typedef short bfv8 __attribute__((ext_vector_type(8)));
typedef short bfv4 __attribute__((ext_vector_type(4)));
typedef float f32x4 __attribute__((ext_vector_type(4)));
typedef unsigned u32x2 __attribute__((ext_vector_type(2)));

__device__ __forceinline__ short f2bf(float f) {
    unsigned u = __builtin_bit_cast(unsigned, f);
    u += 0x7FFFu + ((u >> 16) & 1u);          // RNE
    return (short)(u >> 16);
}
__device__ __forceinline__ float bf2f(short s) {
    unsigned u = ((unsigned)(unsigned short)s) << 16;
    return __builtin_bit_cast(float, u);
}
__device__ __forceinline__ bfv8 pack8(const float4 a, const float4 b) {
    bfv8 r;
    r[0]=f2bf(a.x); r[1]=f2bf(a.y); r[2]=f2bf(a.z); r[3]=f2bf(a.w);
    r[4]=f2bf(b.x); r[5]=f2bf(b.y); r[6]=f2bf(b.z); r[7]=f2bf(b.w);
    return r;
}
__device__ __forceinline__ void gload16(const void* g, void* l) {
    __builtin_amdgcn_global_load_lds(
        (const __attribute__((address_space(1))) unsigned int*)g,
        (__attribute__((address_space(3))) unsigned int*)l, 16, 0, 0);
}
// 2xf32 -> packed bf16 pair (RNE), single instruction  [proven r6]
__device__ __forceinline__ unsigned cvtpk(float a, float b) {
    unsigned r;
    asm("v_cvt_pk_bf16_f32 %0, %1, %2" : "=v"(r) : "v"(a), "v"(b));
    return r;
}
// exp2 via raw v_exp_f32 (s_nop covers trans-op hazard)  [proven r6]
__device__ __forceinline__ float fexp2(float x) {
    float y;
    asm volatile("v_exp_f32 %0, %1\n\ts_nop 1" : "=v"(y) : "v"(x));
    return y;
}
__device__ __forceinline__ float bperm(float v, int addr) {
    return __builtin_bit_cast(float,
        __builtin_amdgcn_ds_bpermute(addr, __builtin_bit_cast(int, v)));
}
__device__ __forceinline__ bfv4 mkfrag(float a, float b, float c, float d) {
    u32x2 t; t[0] = cvtpk(a, b); t[1] = cvtpk(c, d);
    return __builtin_bit_cast(bfv4, t);
}

// ---------------------------------------------------------------------------
// Fused preprocessing: blocks [0, nx) convert x f32->bf16 (1 bfv8/thread,
// nx = numel(x)/8/256 exactly); blocks [nx, ...) transpose-convert the 7
// weight matrices per descriptor table.
// ---------------------------------------------------------------------------
struct TransDesc { const float* src; short* dst; int R, C, b0; };
struct TransArgs { TransDesc t[7]; };

__global__ __launch_bounds__(256) void pre_all(TransArgs ta,
    const float* __restrict__ xsrc, short* __restrict__ xdst, int nx)
{
    __shared__ short tile[64][72];
    int bid = blockIdx.x;
    if (bid < nx) {
        const int i = bid * 256 + threadIdx.x;
        float4 a = ((const float4*)xsrc)[2 * i], b = ((const float4*)xsrc)[2 * i + 1];
        ((bfv8*)xdst)[i] = pack8(a, b);
        return;
    }
    bid -= nx;
    int e = 0;
#pragma unroll
    for (int k = 1; k < 7; ++k) if (bid >= ta.t[k].b0) e = k;
    const TransDesc D = ta.t[e];
    const int loc = bid - D.b0;
    const int cb = D.C >> 6;
    const int by = loc / cb, bx = loc - by * cb;
    const int tid = threadIdx.x;
    const int r0 = by * 64, c0 = bx * 64;
    {
        const int i = tid >> 2, c = (tid & 3) * 16;
        const float* sp = D.src + ((size_t)(r0 + i)) * D.C + c0 + c;
        float4 v0 = ((const float4*)sp)[0], v1 = ((const float4*)sp)[1];
        float4 v2 = ((const float4*)sp)[2], v3 = ((const float4*)sp)[3];
        *(bfv8*)&tile[i][c]     = pack8(v0, v1);
        *(bfv8*)&tile[i][c + 8] = pack8(v2, v3);
    }
    __syncthreads();
    {
        const int j = tid >> 2, rc = (tid & 3) * 16;
        bfv8 g0, g1;
#pragma unroll
        for (int jj = 0; jj < 8; ++jj) { g0[jj] = tile[rc + jj][j]; g1[jj] = tile[rc + 8 + jj][j]; }
        short* dp = D.dst + ((size_t)(c0 + j)) * D.R + r0 + rc;
        *(bfv8*)dp       = g0;
        *(bfv8*)(dp + 8) = g1;
    }
}

// ---------------------------------------------------------------------------
// 2-phase pipelined GEMM: C = A(MxK) * B^T(NxK layout), bf16 in, 128x128 tile,
// BK=32, 4 waves 2x2. OUT_MODE: 0 f32 row-major, 1 bf16 row-major,
// 2 bf16 transposed-to-[b,h,d,t] (V path; b64 stores along t).
// ---------------------------------------------------------------------------
template<int OUT_MODE>
__global__ __launch_bounds__(256) void gemm_bf16(
    const short* __restrict__ A, int lda,
    const short* __restrict__ B, int ldb,
    void* __restrict__ Cptr, int ldc, int K)
{
    __shared__ short As[2][128 * 32];
    __shared__ short Bs[2][128 * 32];
    const int tid = threadIdx.x;
    const int w = tid >> 6, lane = tid & 63;
    const int lr = lane & 15, lg = lane >> 4;
    const int wr = w >> 1, wc = w & 1;
    const size_t bm = (size_t)blockIdx.y * 128, bn = (size_t)blockIdx.x * 128;

    f32x4 acc[4][4] = {};

    const int r0 = tid >> 2, ch = (tid & 3) * 8;
    const short* aB0 = A + (bm + r0) * (size_t)lda + ch;
    const short* aB1 = aB0 + 64 * (size_t)lda;
    const short* bB0 = B + (bn + r0) * (size_t)ldb + ch;
    const short* bB1 = bB0 + 64 * (size_t)ldb;
    const int wof = w * 512;

    gload16(aB0, As[0] + wof);
    gload16(aB1, As[0] + wof + 2048);
    gload16(bB0, Bs[0] + wof);
    gload16(bB1, Bs[0] + wof + 2048);
    __syncthreads();

    int cur = 0;
    for (int k0 = 0; k0 < K; k0 += 32) {
        if (k0 + 32 < K) {
            gload16(aB0 + k0 + 32, As[cur ^ 1] + wof);
            gload16(aB1 + k0 + 32, As[cur ^ 1] + wof + 2048);
            gload16(bB0 + k0 + 32, Bs[cur ^ 1] + wof);
            gload16(bB1 + k0 + 32, Bs[cur ^ 1] + wof + 2048);
        }
        bfv8 af[4], bfr[4];
#pragma unroll
        for (int i = 0; i < 4; ++i) {
            af[i]  = *(const bfv8*)&As[cur][(wr * 64 + i * 16 + lr) * 32 + lg * 8];
            bfr[i] = *(const bfv8*)&Bs[cur][(wc * 64 + i * 16 + lr) * 32 + lg * 8];
        }
#pragma unroll
        for (int i = 0; i < 4; ++i)
#pragma unroll
            for (int j = 0; j < 4; ++j)
                acc[i][j] = __builtin_amdgcn_mfma_f32_16x16x32_bf16(af[i], bfr[j], acc[i][j], 0, 0, 0);
        __syncthreads();
        cur ^= 1;
    }

    if (OUT_MODE == 2) {
        // V path: out[b][h][d][t], b = bm>>11, t = (bm&2047)+wr*64+4*lg+i*16+{0..3}
        short* out = (short*)Cptr;
        const size_t bb = bm >> 11;
        const int tb = (int)(bm & 2047) + wr * 64 + 4 * lg;
        const int colb = (int)bn + wc * 64 + lr;
#pragma unroll
        for (int i = 0; i < 4; ++i)
#pragma unroll
            for (int j = 0; j < 4; ++j) {
                const int c = colb + j * 16;
                const int h = c >> 7, d = c & 127;
                const size_t idx = (((bb * HH + h) * 128 + d) << 11) + tb + i * 16;
                *(bfv4*)&out[idx] = mkfrag(acc[i][j][0], acc[i][j][1], acc[i][j][2], acc[i][j][3]);
            }
    } else {
        const size_t crow = bm + wr * 64 + 4 * lg;
        const size_t ccol = bn + wc * 64 + lr;
#pragma unroll
        for (int i = 0; i < 4; ++i)
#pragma unroll
            for (int j = 0; j < 4; ++j)
#pragma unroll
                for (int r = 0; r < 4; ++r) {
                    size_t off = (crow + i * 16 + r) * (size_t)ldc + ccol + j * 16;
                    if (OUT_MODE == 0) ((float*)Cptr)[off] = acc[i][j][r];
                    else               ((short*)Cptr)[off] = f2bf(acc[i][j][r]);
                }
    }
}

// ---------------------------------------------------------------------------
// k_content GEMM with fused rope(k_pe) add + rmsnorm epilogue.
// A = kv_content [4096][2048(lda)], B = wk_b^T [2048][768], K=768.
// Tile 128x128: rows = 128 tokens, cols = exactly one head (2048/128=16).
// Epilogue: acc += rope(KPE tile); per-row (d=128) rmsnorm; write KB [b,h,t,d].
// ---------------------------------------------------------------------------
__global__ __launch_bounds__(256) void gemm_kc_rope(
    const short* __restrict__ A, int lda,
    const short* __restrict__ B, int ldb,
    const short* __restrict__ KPE,           // [4096][2048] bf16
    const float* __restrict__ cosb,          // [2048][64]
    const float* __restrict__ sinb,
    short* __restrict__ KB, int K)
{
    __shared__ short As[2][128 * 32];
    __shared__ short Bs[2][128 * 32];
    const int tid = threadIdx.x;
    const int w = tid >> 6, lane = tid & 63;
    const int lr = lane & 15, lg = lane >> 4;
    const int wr = w >> 1, wc = w & 1;
    const size_t bm = (size_t)blockIdx.y * 128, bn = (size_t)blockIdx.x * 128;

    f32x4 acc[4][4] = {};

    const int r0 = tid >> 2, ch = (tid & 3) * 8;
    const short* aB0 = A + (bm + r0) * (size_t)lda + ch;
    const short* aB1 = aB0 + 64 * (size_t)lda;
    const short* bB0 = B + (bn + r0) * (size_t)ldb + ch;
    const short* bB1 = bB0 + 64 * (size_t)ldb;
    const int wof = w * 512;

    gload16(aB0, As[0] + wof);
    gload16(aB1, As[0] + wof + 2048);
    gload16(bB0, Bs[0] + wof);
    gload16(bB1, Bs[0] + wof + 2048);
    __syncthreads();

    int cur = 0;
    for (int k0 = 0; k0 < K; k0 += 32) {
        if (k0 + 32 < K) {
            gload16(aB0 + k0 + 32, As[cur ^ 1] + wof);
            gload16(aB1 + k0 + 32, As[cur ^ 1] + wof + 2048);
            gload16(bB0 + k0 + 32, Bs[cur ^ 1] + wof);
            gload16(bB1 + k0 + 32, Bs[cur ^ 1] + wof + 2048);
        }
        bfv8 af[4], bfr[4];
#pragma unroll
        for (int i = 0; i < 4; ++i) {
            af[i]  = *(const bfv8*)&As[cur][(wr * 64 + i * 16 + lr) * 32 + lg * 8];
            bfr[i] = *(const bfv8*)&Bs[cur][(wc * 64 + i * 16 + lr) * 32 + lg * 8];
        }
#pragma unroll
        for (int i = 0; i < 4; ++i)
#pragma unroll
            for (int j = 0; j < 4; ++j)
                acc[i][j] = __builtin_amdgcn_mfma_f32_16x16x32_bf16(af[i], bfr[j], acc[i][j], 0, 0, 0);
        __syncthreads();
        cur ^= 1;
    }

    // ---- epilogue: rope(KPE) add ----
    const int hh = (int)(bn >> 7);
#pragma unroll
    for (int i = 0; i < 4; ++i)
#pragma unroll
        for (int r = 0; r < 4; ++r) {
            const int R = (int)bm + wr * 64 + i * 16 + 4 * lg + r;   // global token row
            const int t = R & (TT - 1);
#pragma unroll
            for (int j = 0; j < 4; ++j) {
                const int colg = (int)bn + wc * 64 + j * 16 + lr;
                const int d64  = j * 16 + lr;                         // d mod 64
                const float pe_self = bf2f(KPE[(size_t)R * 2048 + colg]);
                const float pe_part = bf2f(KPE[(size_t)R * 2048 + colg + (wc ? -64 : 64)]);
                const float c = cosb[t * 64 + d64], s = sinb[t * 64 + d64];
                const float rope = wc ? (pe_self * c - pe_part * s)
                                      : (pe_self * c + pe_part * s);
                acc[i][j][r] += rope;
            }
        }

    // ---- per-row sum of squares: lr-group shfl reduce + cross-wave LDS ----
    float ps[4][4];
#pragma unroll
    for (int i = 0; i < 4; ++i)
#pragma unroll
        for (int r = 0; r < 4; ++r) {
            float v = acc[i][0][r] * acc[i][0][r];
            v = fmaf(acc[i][1][r], acc[i][1][r], v);
            v = fmaf(acc[i][2][r], acc[i][2][r], v);
            v = fmaf(acc[i][3][r], acc[i][3][r], v);
            ps[i][r] = v;
        }
#pragma unroll
    for (int off = 1; off < 16; off <<= 1)
#pragma unroll
        for (int i = 0; i < 4; ++i)
#pragma unroll
            for (int r = 0; r < 4; ++r) ps[i][r] += __shfl_xor(ps[i][r], off);

    float* rbuf = (float*)As;   // safe: all LDS reads done (final barrier in loop)
    if (lr == 0) {
#pragma unroll
        for (int i = 0; i < 4; ++i)
#pragma unroll
            for (int r = 0; r < 4; ++r)
                rbuf[((wc * 2 + wr) * 4 + lg) * 16 + i * 4 + r] = ps[i][r];
    }
    __syncthreads();

#pragma unroll
    for (int i = 0; i < 4; ++i)
#pragma unroll
        for (int r = 0; r < 4; ++r) {
            const float tot = ps[i][r] + rbuf[(((wc ^ 1) * 2 + wr) * 4 + lg) * 16 + i * 4 + r];
            const float rr = rsqrtf(tot * (1.0f / 128.0f) + EPSV);
            const int R = (int)bm + wr * 64 + i * 16 + 4 * lg + r;
            const int t = R & (TT - 1), bb = R >> 11;
            const size_t ob = (((size_t)bb * HH + hh) * TT + t) * 128 + wc * 64 + lr;
#pragma unroll
            for (int j = 0; j < 4; ++j)
                KB[ob + j * 16] = f2bf(acc[i][j][r] * rr);
        }
}

// ---------------------------------------------------------------------------
// attn helpers. Swapped-QK layout: s[ct][r] at lane (lr,lg) = S[key = ct*16 +
// 4*lg + r][q = lr] (q local to wave's 16 rows, key local to 64-tile).
// ---------------------------------------------------------------------------
__device__ __forceinline__ void qk_dual(const short* __restrict__ Ks,
    const bfv8 aq1[4], const bfv8 aq2[4], f32x4 s1[4], f32x4 s2[4], int lr, int lg)
{
    const int swz = lr & 7;
#pragma unroll
    for (int ct = 0; ct < 4; ++ct) {
        f32x4 a1 = {0.f, 0.f, 0.f, 0.f}, a2 = {0.f, 0.f, 0.f, 0.f};
        const int row = ct * 16 + lr;
#pragma unroll
        for (int ks = 0; ks < 4; ++ks) {
            const bfv8 bk = *(const bfv8*)&Ks[row * 128 + (((ks * 4 + lg) ^ swz) * 8)];
            a1 = __builtin_amdgcn_mfma_f32_16x16x32_bf16(bk, aq1[ks], a1, 0, 0, 0);
            a2 = __builtin_amdgcn_mfma_f32_16x16x32_bf16(bk, aq2[ks], a2, 0, 0, 0);
        }
        s1[ct] = a1; s2[ct] = a2;
    }
}

__device__ __forceinline__ void qk_one(const short* __restrict__ Ks,
    const bfv8 aq[4], f32x4 s[4], int lr, int lg)
{
    const int swz = lr & 7;
#pragma unroll
    for (int ct = 0; ct < 4; ++ct) {
        f32x4 a = {0.f, 0.f, 0.f, 0.f};
        const int row = ct * 16 + lr;
#pragma unroll
        for (int ks = 0; ks < 4; ++ks) {
            const bfv8 bk = *(const bfv8*)&Ks[row * 128 + (((ks * 4 + lg) ^ swz) * 8)];
            a = __builtin_amdgcn_mfma_f32_16x16x32_bf16(bk, aq[ks], a, 0, 0, 0);
        }
        s[ct] = a;
    }
}

// diag mask: key local (ct*16+4*lg+r) > q local (w*16+lr)
__device__ __forceinline__ void mask_diag(f32x4 s[4], int lr, int lg, int w)
{
    const int qq = w * 16 + lr;
#pragma unroll
    for (int ct = 0; ct < 4; ++ct)
#pragma unroll
        for (int r = 0; r < 4; ++r)
            if (ct * 16 + 4 * lg + r > qq) s[ct][r] = -__builtin_inff();
}

// per-lane online softmax for q = lr; m,l per-lane scalars (replicated over lg)
__device__ __forceinline__ void softmax_lane(f32x4 s[4], float& m, float& l,
                                             f32x4 o[8], int a0)
{
    float c0 = fmaxf(fmaxf(s[0][0], s[0][1]), fmaxf(s[0][2], s[0][3]));
    float c1 = fmaxf(fmaxf(s[1][0], s[1][1]), fmaxf(s[1][2], s[1][3]));
    float c2 = fmaxf(fmaxf(s[2][0], s[2][1]), fmaxf(s[2][2], s[2][3]));
    float c3 = fmaxf(fmaxf(s[3][0], s[3][1]), fmaxf(s[3][2], s[3][3]));
    float mt = fmaxf(fmaxf(c0, c1), fmaxf(c2, c3));
    mt = fmaxf(mt, __shfl_xor(mt, 16));
    mt = fmaxf(mt, __shfl_xor(mt, 32));
    if (!__all(mt - m <= THRL)) {
        float mn = fmaxf(m, mt);
        float alpha = fexp2(m - mn);
        m = mn;
        l *= alpha;
        // o[dt][j] holds q = 4*lg + j; alpha for that q lives at lane lg*20 + j
        float av0 = bperm(alpha, a0);
        float av1 = bperm(alpha, a0 + 4);
        float av2 = bperm(alpha, a0 + 8);
        float av3 = bperm(alpha, a0 + 12);
#pragma unroll
        for (int dt = 0; dt < 8; ++dt) {
            o[dt][0] *= av0; o[dt][1] *= av1;
            o[dt][2] *= av2; o[dt][3] *= av3;
        }
    }
    f32x4 acc = {0.f, 0.f, 0.f, 0.f};
#pragma unroll
    for (int ct = 0; ct < 4; ++ct) {
#pragma unroll
        for (int r = 0; r < 4; ++r) s[ct][r] = fexp2(s[ct][r] - m);
        acc += s[ct];
    }
    float rs = (acc[0] + acc[1]) + (acc[2] + acc[3]);
    rs += __shfl_xor(rs, 16);
    rs += __shfl_xor(rs, 32);
    l += rs;
}

// P store: lane's 4 keys per ct are consecutive -> one b64 write per ct
__device__ __forceinline__ void p_store(short (&Psw)[16][72], const f32x4 s[4],
                                        int lr, int lg)
{
#pragma unroll
    for (int ct = 0; ct < 4; ++ct)
        *(bfv4*)&Psw[lr][ct * 16 + 4 * lg] = mkfrag(s[ct][0], s[ct][1], s[ct][2], s[ct][3]);
}

// PV via proven 16x16x32: A = P (LDS, A-layout), B = V rows (d). Shares bv.
__device__ __forceinline__ void pv_dual(const short* __restrict__ Vs,
    const short (&P1)[16][72], const short (&P2)[16][72],
    f32x4 o1[8], f32x4 o2[8], int lr, int lg)
{
    const bfv8 pa0 = *(const bfv8*)&P1[lr][lg * 8];
    const bfv8 pa1 = *(const bfv8*)&P1[lr][32 + lg * 8];
    const bfv8 pb0 = *(const bfv8*)&P2[lr][lg * 8];
    const bfv8 pb1 = *(const bfv8*)&P2[lr][32 + lg * 8];
    const int swz = lr & 7;
#pragma unroll
    for (int dt = 0; dt < 8; ++dt) {
        const int row = dt * 16 + lr;
        const bfv8 bv0 = *(const bfv8*)&Vs[row * 64 + ((lg ^ swz) * 8)];
        const bfv8 bv1 = *(const bfv8*)&Vs[row * 64 + (((4 + lg) ^ swz) * 8)];
        o1[dt] = __builtin_amdgcn_mfma_f32_16x16x32_bf16(pa0, bv0, o1[dt], 0, 0, 0);
        o1[dt] = __builtin_amdgcn_mfma_f32_16x16x32_bf16(pa1, bv1, o1[dt], 0, 0, 0);
        o2[dt] = __builtin_amdgcn_mfma_f32_16x16x32_bf16(pb0, bv0, o2[dt], 0, 0, 0);
        o2[dt] = __builtin_amdgcn_mfma_f32_16x16x32_bf16(pb1, bv1, o2[dt], 0, 0, 0);
    }
}

__device__ __forceinline__ void pv_one(const short* __restrict__ Vs,
    const short (&P2)[16][72], f32x4 o[8], int lr, int lg)
{
    const bfv8 pa0 = *(const bfv8*)&P2[lr][lg * 8];
    const bfv8 pa1 = *(const bfv8*)&P2[lr][32 + lg * 8];
    const int swz = lr & 7;
#pragma unroll
    for (int dt = 0; dt < 8; ++dt) {
        const int row = dt * 16 + lr;
        const bfv8 bv0 = *(const bfv8*)&Vs[row * 64 + ((lg ^ swz) * 8)];
        const bfv8 bv1 = *(const bfv8*)&Vs[row * 64 + (((4 + lg) ^ swz) * 8)];
        o[dt] = __builtin_amdgcn_mfma_f32_16x16x32_bf16(pa0, bv0, o[dt], 0, 0, 0);
        o[dt] = __builtin_amdgcn_mfma_f32_16x16x32_bf16(pa1, bv1, o[dt], 0, 0, 0);
    }
}

// ---------------------------------------------------------------------------
// Adjacent-pair causal flash attention: block handles q-tiles {2pi, 2pi+1};
// single-stream segment is exactly 1 step. Longest blocks dispatched first.
// Swapped-QK softmax (per-lane), proven 16x16x32 PV, single-buffer staging,
// XCD-clustered remap, fused Q-rmsnorm.
// ---------------------------------------------------------------------------
__global__ __launch_bounds__(256) void attn_kernel(
    const short* __restrict__ qg, const short* __restrict__ kg,
    const short* __restrict__ vg, short* __restrict__ y)
{
    __shared__ short Ks[64 * 128];
    __shared__ short Vs[128 * 64];
    __shared__ short Ps1[4][16][72];
    __shared__ short Ps2[4][16][72];

    const int lin = blockIdx.x + 16 * blockIdx.y + 256 * blockIdx.z;
    const int work = (lin & 7) * 64 + (lin >> 3);
    const int pi = 15 - (work & 15);          // longest blocks first
    const int h = (work >> 4) & 15, b = work >> 8;
    const int qt1 = 2 * pi, qt2 = 2 * pi + 1;
    const int tid = threadIdx.x, w = tid >> 6, lane = tid & 63;
    const int lr = lane & 15, lg = lane >> 4;
    const int a0 = lg * 80;   // byte addr of lane lg*20 (q = 4*lg) for bperm

    const size_t tok0 = ((size_t)b * HH + h) * TT;

    bfv8 aq1[4], aq2[4];
    {
        const size_t q1 = ((size_t)b * TT + qt1 * 64 + w * 16 + lr) * 2048 + h * 128;
        const size_t q2 = ((size_t)b * TT + qt2 * 64 + w * 16 + lr) * 2048 + h * 128;
#pragma unroll
        for (int ks = 0; ks < 4; ++ks) {
            aq1[ks] = *(const bfv8*)&qg[q1 + ks * 32 + lg * 8];
            aq2[ks] = *(const bfv8*)&qg[q2 + ks * 32 + lg * 8];
        }
        // fused rmsnorm * (1/sqrt(D)) * log2(e)
#pragma unroll
        for (int st = 0; st < 2; ++st) {
            bfv8* aq = st ? aq2 : aq1;
            float ss = 0.f;
#pragma unroll
            for (int ks = 0; ks < 4; ++ks)
#pragma unroll
                for (int j = 0; j < 8; ++j) { float f = bf2f(aq[ks][j]); ss = fmaf(f, f, ss); }
            ss += __shfl_xor(ss, 16);
            ss += __shfl_xor(ss, 32);
            float rr = rsqrtf(ss * (1.0f / 128.0f) + EPSV) * (QSCALE * LOG2E);
#pragma unroll
            for (int ks = 0; ks < 4; ++ks)
#pragma unroll
                for (int j = 0; j < 4; ++j) {
                    unsigned u = cvtpk(bf2f(aq[ks][2 * j]) * rr, bf2f(aq[ks][2 * j + 1]) * rr);
                    aq[ks][2 * j]     = (short)u;
                    aq[ks][2 * j + 1] = (short)(u >> 16);
                }
        }
    }

    f32x4 o1[8] = {}; f32x4 o2[8] = {};
    float m1 = -__builtin_inff(), m2 = -__builtin_inff();
    float l1 = 0.f, l2 = 0.f;

    const size_t vhead = ((size_t)b * HH + h) * (size_t)128 * TT;
    const int krow = tid >> 4, kub = (tid & 15) ^ (krow & 7);
    const int vrow = tid >> 3, vub = (tid & 7) ^ (vrow & 7);
    const int wof = w * 512;

    for (int kt = 0; kt <= qt2; ++kt) {
        {
            const size_t kbase = (tok0 + kt * 64) * 128;
#pragma unroll
            for (int p = 0; p < 4; ++p) {
                gload16(kg + kbase + (p * 16 + krow) * 128 + kub * 8, Ks + wof + p * 2048);
                gload16(vg + vhead + (size_t)(p * 32 + vrow) * TT + kt * 64 + vub * 8,
                        Vs + wof + p * 2048);
            }
        }
        __syncthreads();

        if (kt <= qt1) {
            f32x4 s1[4], s2[4];
            qk_dual(Ks, aq1, aq2, s1, s2, lr, lg);
            if (kt == qt1) mask_diag(s1, lr, lg, w);
            softmax_lane(s1, m1, l1, o1, a0);
            softmax_lane(s2, m2, l2, o2, a0);
            p_store(Ps1[w], s1, lr, lg);
            p_store(Ps2[w], s2, lr, lg);
            pv_dual(Vs, Ps1[w], Ps2[w], o1, o2, lr, lg);
        } else {
            f32x4 s2[4];
            qk_one(Ks, aq2, s2, lr, lg);
            if (kt == qt2) mask_diag(s2, lr, lg, w);
            softmax_lane(s2, m2, l2, o2, a0);
            p_store(Ps2[w], s2, lr, lg);
            pv_one(Vs, Ps2[w], o2, lr, lg);
        }
        __syncthreads();
    }

    // epilogue: o[dt][r] is q = 4*lg + r; 1/l for that q lives at lane lg*20 + r
    float n1 = 1.0f / l1, n2 = 1.0f / l2;
    float iv1[4], iv2[4];
#pragma unroll
    for (int r = 0; r < 4; ++r) {
        iv1[r] = bperm(n1, a0 + 4 * r);
        iv2[r] = bperm(n2, a0 + 4 * r);
    }
#pragma unroll
    for (int r = 0; r < 4; ++r) {
        const size_t y1 = ((size_t)b * TT + qt1 * 64 + w * 16 + 4 * lg + r) * 2048 + h * 128 + lr;
        const size_t y2 = ((size_t)b * TT + qt2 * 64 + w * 16 + 4 * lg + r) * 2048 + h * 128 + lr;
#pragma unroll
        for (int dt = 0; dt < 8; ++dt) {
            y[y1 + dt * 16] = f2bf(o1[dt][r] * iv1[r]);
            y[y2 + dt * 16] = f2bf(o2[dt][r] * iv2[r]);
        }
    }
}

// ---------------------------------------------------------------------------
extern "C" void kernel_launch(void* const* d_in, const int* in_sizes, int n_in,
                              void* d_out, int out_size, void* d_ws, size_t ws_size,
                              hipStream_t stream)
{
    const float* x      = (const float*)d_in[0];
    const float* cosb   = (const float*)d_in[1];
    const float* sinb   = (const float*)d_in[2];
    const float* wq_a   = (const float*)d_in[3];
    const float* wq_b   = (const float*)d_in[4];
    const float* wkv_a  = (const float*)d_in[5];
    const float* wk_b   = (const float*)d_in[6];
    const float* wkpe_b = (const float*)d_in[7];
    const float* wv_b   = (const float*)d_in[8];
    const float* wo     = (const float*)d_in[9];

    short* wsp = (short*)d_ws;
    short* W1  = wsp;                 // [2048][2048]  [wq_a^T ; wkv_a^T]
    short* W2  = wsp + 4194304;       // [4096][768]   [wk_b^T ; wv_b^T]
    short* W3  = wsp + 7340032;       // [2048][256]   wkpe_b^T
    short* W4  = wsp + 7864320;       // [2048][1024]  wq_b^T
    short* W5  = wsp + 9961472;       // [2048][2048]  wo^T
    short* C1  = wsp + 14155776;      // [4096][2048]  qlat|kvlat; later y
    short* KPE = wsp + 30932992;      // [4096][2048]  k_pe; later qbuf
    short* KB  = wsp + 39321600;      // [b,h,t,d]
    short* VB  = wsp + 47710208;      // [b,h,d,t]
    short* XB  = (short*)d_out;       // x as bf16 (d_out reused as scratch)

    dim3 blk(256);

    // fused preprocessing: convx 4096 blocks + 7 transposes 3456 blocks
    TransArgs ta;
    ta.t[0] = {wq_a,   W1,                2048, 1024,    0};
    ta.t[1] = {wkv_a,  W1 + 1024 * 2048,  2048, 1024,  512};
    ta.t[2] = {wk_b,   W2,                 768, 2048, 1024};
    ta.t[3] = {wv_b,   W2 + 2048 * 768,    768, 2048, 1408};
    ta.t[4] = {wkpe_b, W3,                 256, 2048, 1792};
    ta.t[5] = {wq_b,   W4,                1024, 2048, 1920};
    ta.t[6] = {wo,     W5,                2048, 2048, 2432};
    pre_all<<<4096 + 3456, blk, 0, stream>>>(ta, x, XB, 4096);

    // [qlat|kvlat] = x @ [wq_a|wkv_a]
    gemm_bf16<1><<<dim3(16, 32), blk, 0, stream>>>(XB, 2048, W1, 2048, C1, 2048, 2048);
    // k_pe = kv_pe @ wkpe_b
    gemm_bf16<1><<<dim3(16, 32), blk, 0, stream>>>(C1 + 1024, 2048, W3, 256, KPE, 2048, 256);
    // k = rmsnorm(kv_content @ wk_b + rope(k_pe)) -> KB [b,h,t,d]  (fused)
    gemm_kc_rope<<<dim3(16, 32), blk, 0, stream>>>(C1 + 1280, 2048, W2, 768,
                                                   KPE, cosb, sinb, KB, 768);
    // v = kv_content @ wv_b, stored directly as [b,h,d,t]
    gemm_bf16<2><<<dim3(16, 32), blk, 0, stream>>>(C1 + 1280, 2048, W2 + 2048 * 768, 768, VB, 0, 768);

    // qbuf = qlat @ wq_b  (into KPE slot -- after kc_rope consumed KPE)
    gemm_bf16<1><<<dim3(16, 32), blk, 0, stream>>>(C1, 2048, W4, 1024, KPE, 2048, 1024);

    // attention: y into C1 slot
    attn_kernel<<<dim3(16, 16, 2), blk, 0, stream>>>(KPE, KB, VB, C1);

    // out = y @ wo
    gemm_bf16<0><<<dim3(16, 32), blk, 0, stream>>>(C1, 2048, W5, 2048, d_out, 2048, 2048);
}

// Round 13
// 315.901 us; speedup vs baseline: 1.1077x; 1.1077x over previous
//
#include <hip/hip_runtime.h>
#include <cstddef>
#include <cstdint>

#define TT 2048
#define HH 16
#define EPSV 1.1920929e-07f
#define QSCALE 0.08838834764831845f   // 1/sqrt(128)
#define LOG2E 1.4426950408889634f
#define THRL 11.0f                    // defer-rescale threshold (log2 units)

typedef short bfv8 __attribute__((ext_vector_type(8)));
typedef short bfv4 __attribute__((ext_vector_type(4)));
typedef float f32x4 __attribute__((ext_vector_type(4)));
typedef unsigned u32x2 __attribute__((ext_vector_type(2)));

__device__ __forceinline__ short f2bf(float f) {
    unsigned u = __builtin_bit_cast(unsigned, f);
    u += 0x7FFFu + ((u >> 16) & 1u);          // RNE
    return (short)(u >> 16);
}
__device__ __forceinline__ float bf2f(short s) {
    unsigned u = ((unsigned)(unsigned short)s) << 16;
    return __builtin_bit_cast(float, u);
}
__device__ __forceinline__ bfv8 pack8(const float4 a, const float4 b) {
    bfv8 r;
    r[0]=f2bf(a.x); r[1]=f2bf(a.y); r[2]=f2bf(a.z); r[3]=f2bf(a.w);
    r[4]=f2bf(b.x); r[5]=f2bf(b.y); r[6]=f2bf(b.z); r[7]=f2bf(b.w);
    return r;
}
__device__ __forceinline__ void gload16(const void* g, void* l) {
    __builtin_amdgcn_global_load_lds(
        (const __attribute__((address_space(1))) unsigned int*)g,
        (__attribute__((address_space(3))) unsigned int*)l, 16, 0, 0);
}
// 2xf32 -> packed bf16 pair (RNE), single instruction  [proven r6]
__device__ __forceinline__ unsigned cvtpk(float a, float b) {
    unsigned r;
    asm("v_cvt_pk_bf16_f32 %0, %1, %2" : "=v"(r) : "v"(a), "v"(b));
    return r;
}
// exp2 via raw v_exp_f32 (s_nop covers trans-op hazard)  [proven r6]
__device__ __forceinline__ float fexp2(float x) {
    float y;
    asm volatile("v_exp_f32 %0, %1\n\ts_nop 1" : "=v"(y) : "v"(x));
    return y;
}
__device__ __forceinline__ bfv4 mkfrag(float a, float b, float c, float d) {
    u32x2 t; t[0] = cvtpk(a, b); t[1] = cvtpk(c, d);
    return __builtin_bit_cast(bfv4, t);
}

// ---------------------------------------------------------------------------
// Fused preprocessing (r11): convx + 7 weight transposes.
// ---------------------------------------------------------------------------
struct TransDesc { const float* src; short* dst; int R, C, b0; };
struct TransArgs { TransDesc t[7]; };

__global__ __launch_bounds__(256) void pre_all(TransArgs ta,
    const float* __restrict__ xsrc, short* __restrict__ xdst, int nx)
{
    __shared__ short tile[64][72];
    int bid = blockIdx.x;
    if (bid < nx) {
        const int i = bid * 256 + threadIdx.x;
        float4 a = ((const float4*)xsrc)[2 * i], b = ((const float4*)xsrc)[2 * i + 1];
        ((bfv8*)xdst)[i] = pack8(a, b);
        return;
    }
    bid -= nx;
    int e = 0;
#pragma unroll
    for (int k = 1; k < 7; ++k) if (bid >= ta.t[k].b0) e = k;
    const TransDesc D = ta.t[e];
    const int loc = bid - D.b0;
    const int cb = D.C >> 6;
    const int by = loc / cb, bx = loc - by * cb;
    const int tid = threadIdx.x;
    const int r0 = by * 64, c0 = bx * 64;
    {
        const int i = tid >> 2, c = (tid & 3) * 16;
        const float* sp = D.src + ((size_t)(r0 + i)) * D.C + c0 + c;
        float4 v0 = ((const float4*)sp)[0], v1 = ((const float4*)sp)[1];
        float4 v2 = ((const float4*)sp)[2], v3 = ((const float4*)sp)[3];
        *(bfv8*)&tile[i][c]     = pack8(v0, v1);
        *(bfv8*)&tile[i][c + 8] = pack8(v2, v3);
    }
    __syncthreads();
    {
        const int j = tid >> 2, rc = (tid & 3) * 16;
        bfv8 g0, g1;
#pragma unroll
        for (int jj = 0; jj < 8; ++jj) { g0[jj] = tile[rc + jj][j]; g1[jj] = tile[rc + 8 + jj][j]; }
        short* dp = D.dst + ((size_t)(c0 + j)) * D.R + r0 + rc;
        *(bfv8*)dp       = g0;
        *(bfv8*)(dp + 8) = g1;
    }
}

// ---------------------------------------------------------------------------
// 2-phase pipelined GEMM (r11): OUT_MODE 0 f32, 1 bf16, 2 bf16 -> [b,h,d,t].
// ---------------------------------------------------------------------------
template<int OUT_MODE>
__global__ __launch_bounds__(256) void gemm_bf16(
    const short* __restrict__ A, int lda,
    const short* __restrict__ B, int ldb,
    void* __restrict__ Cptr, int ldc, int K)
{
    __shared__ short As[2][128 * 32];
    __shared__ short Bs[2][128 * 32];
    const int tid = threadIdx.x;
    const int w = tid >> 6, lane = tid & 63;
    const int lr = lane & 15, lg = lane >> 4;
    const int wr = w >> 1, wc = w & 1;
    const size_t bm = (size_t)blockIdx.y * 128, bn = (size_t)blockIdx.x * 128;

    f32x4 acc[4][4] = {};

    const int r0 = tid >> 2, ch = (tid & 3) * 8;
    const short* aB0 = A + (bm + r0) * (size_t)lda + ch;
    const short* aB1 = aB0 + 64 * (size_t)lda;
    const short* bB0 = B + (bn + r0) * (size_t)ldb + ch;
    const short* bB1 = bB0 + 64 * (size_t)ldb;
    const int wof = w * 512;

    gload16(aB0, As[0] + wof);
    gload16(aB1, As[0] + wof + 2048);
    gload16(bB0, Bs[0] + wof);
    gload16(bB1, Bs[0] + wof + 2048);
    __syncthreads();

    int cur = 0;
    for (int k0 = 0; k0 < K; k0 += 32) {
        if (k0 + 32 < K) {
            gload16(aB0 + k0 + 32, As[cur ^ 1] + wof);
            gload16(aB1 + k0 + 32, As[cur ^ 1] + wof + 2048);
            gload16(bB0 + k0 + 32, Bs[cur ^ 1] + wof);
            gload16(bB1 + k0 + 32, Bs[cur ^ 1] + wof + 2048);
        }
        bfv8 af[4], bfr[4];
#pragma unroll
        for (int i = 0; i < 4; ++i) {
            af[i]  = *(const bfv8*)&As[cur][(wr * 64 + i * 16 + lr) * 32 + lg * 8];
            bfr[i] = *(const bfv8*)&Bs[cur][(wc * 64 + i * 16 + lr) * 32 + lg * 8];
        }
#pragma unroll
        for (int i = 0; i < 4; ++i)
#pragma unroll
            for (int j = 0; j < 4; ++j)
                acc[i][j] = __builtin_amdgcn_mfma_f32_16x16x32_bf16(af[i], bfr[j], acc[i][j], 0, 0, 0);
        __syncthreads();
        cur ^= 1;
    }

    if (OUT_MODE == 2) {
        short* out = (short*)Cptr;
        const size_t bb = bm >> 11;
        const int tb = (int)(bm & 2047) + wr * 64 + 4 * lg;
        const int colb = (int)bn + wc * 64 + lr;
#pragma unroll
        for (int i = 0; i < 4; ++i)
#pragma unroll
            for (int j = 0; j < 4; ++j) {
                const int c = colb + j * 16;
                const int h = c >> 7, d = c & 127;
                const size_t idx = (((bb * HH + h) * 128 + d) << 11) + tb + i * 16;
                *(bfv4*)&out[idx] = mkfrag(acc[i][j][0], acc[i][j][1], acc[i][j][2], acc[i][j][3]);
            }
    } else {
        const size_t crow = bm + wr * 64 + 4 * lg;
        const size_t ccol = bn + wc * 64 + lr;
#pragma unroll
        for (int i = 0; i < 4; ++i)
#pragma unroll
            for (int j = 0; j < 4; ++j)
#pragma unroll
                for (int r = 0; r < 4; ++r) {
                    size_t off = (crow + i * 16 + r) * (size_t)ldc + ccol + j * 16;
                    if (OUT_MODE == 0) ((float*)Cptr)[off] = acc[i][j][r];
                    else               ((short*)Cptr)[off] = f2bf(acc[i][j][r]);
                }
    }
}

// ---------------------------------------------------------------------------
// k = rmsnorm(k_content + rope(k_pe)); bf16 in, bf16 head-major out [b,h,t,d]
// ---------------------------------------------------------------------------
__global__ __launch_bounds__(256) void finalize_k(
    const short* __restrict__ kc, const short* __restrict__ pe,
    const float* __restrict__ cosb, const float* __restrict__ sinb,
    short* __restrict__ kb)
{
    const int gw = blockIdx.x * 4 + (threadIdx.x >> 6);
    const int l = threadIdx.x & 63;
    const int r = gw >> 4, h = gw & 15;
    const int t = r & (TT - 1), b = r >> 11;
    const size_t kcb = (size_t)r * 2048 + h * 128;
    const size_t peb = (size_t)r * 2048 + h * 128;

    float x1 = bf2f(pe[peb + l]), x2 = bf2f(pe[peb + 64 + l]);
    float c = cosb[t * 64 + l], s = sinb[t * 64 + l];
    float lo = bf2f(kc[kcb + l])      + x1 * c + x2 * s;
    float hi = bf2f(kc[kcb + 64 + l]) - x1 * s + x2 * c;

    float ss = lo * lo + hi * hi;
#pragma unroll
    for (int o = 32; o; o >>= 1) ss += __shfl_xor(ss, o);
    float rr = rsqrtf(ss * (1.0f / 128.0f) + EPSV);
    const size_t ob = (((size_t)b * HH + h) * TT + t) * 128;
    kb[ob + l]      = f2bf(lo * rr);
    kb[ob + 64 + l] = f2bf(hi * rr);
}

// ---------------------------------------------------------------------------
// attn helpers (r11, unchanged)
// ---------------------------------------------------------------------------
__device__ __forceinline__ void qk_dual(const short* __restrict__ Ks,
    const bfv8 aq1[4], const bfv8 aq2[4], f32x4 s1[4], f32x4 s2[4], int lr, int lg)
{
    const int swz = lr & 7;
#pragma unroll
    for (int ct = 0; ct < 4; ++ct) {
        f32x4 a1 = {0.f, 0.f, 0.f, 0.f}, a2 = {0.f, 0.f, 0.f, 0.f};
        const int row = ct * 16 + lr;
#pragma unroll
        for (int ks = 0; ks < 4; ++ks) {
            const bfv8 bk = *(const bfv8*)&Ks[row * 128 + (((ks * 4 + lg) ^ swz) * 8)];
            a1 = __builtin_amdgcn_mfma_f32_16x16x32_bf16(bk, aq1[ks], a1, 0, 0, 0);
            a2 = __builtin_amdgcn_mfma_f32_16x16x32_bf16(bk, aq2[ks], a2, 0, 0, 0);
        }
        s1[ct] = a1; s2[ct] = a2;
    }
}

__device__ __forceinline__ void qk_one(const short* __restrict__ Ks,
    const bfv8 aq[4], f32x4 s[4], int lr, int lg)
{
    const int swz = lr & 7;
#pragma unroll
    for (int ct = 0; ct < 4; ++ct) {
        f32x4 a = {0.f, 0.f, 0.f, 0.f};
        const int row = ct * 16 + lr;
#pragma unroll
        for (int ks = 0; ks < 4; ++ks) {
            const bfv8 bk = *(const bfv8*)&Ks[row * 128 + (((ks * 4 + lg) ^ swz) * 8)];
            a = __builtin_amdgcn_mfma_f32_16x16x32_bf16(bk, aq[ks], a, 0, 0, 0);
        }
        s[ct] = a;
    }
}

__device__ __forceinline__ void mask_diag(f32x4 s[4], int lr, int lg, int w)
{
    const int qq = w * 16 + lr;
#pragma unroll
    for (int ct = 0; ct < 4; ++ct)
#pragma unroll
        for (int r = 0; r < 4; ++r)
            if (ct * 16 + 4 * lg + r > qq) s[ct][r] = -__builtin_inff();
}

__device__ __forceinline__ void softmax_lane(f32x4 s[4], float& m, float& l,
                                             f32x4 o[8], int a0)
{
    float c0 = fmaxf(fmaxf(s[0][0], s[0][1]), fmaxf(s[0][2], s[0][3]));
    float c1 = fmaxf(fmaxf(s[1][0], s[1][1]), fmaxf(s[1][2], s[1][3]));
    float c2 = fmaxf(fmaxf(s[2][0], s[2][1]), fmaxf(s[2][2], s[2][3]));
    float c3 = fmaxf(fmaxf(s[3][0], s[3][1]), fmaxf(s[3][2], s[3][3]));
    float mt = fmaxf(fmaxf(c0, c1), fmaxf(c2, c3));
    mt = fmaxf(mt, __shfl_xor(mt, 16));
    mt = fmaxf(mt, __shfl_xor(mt, 32));
    if (!__all(mt - m <= THRL)) {
        float mn = fmaxf(m, mt);
        float alpha = fexp2(m - mn);
        m = mn;
        l *= alpha;
        float av0 = __builtin_bit_cast(float, __builtin_amdgcn_ds_bpermute(a0,      __builtin_bit_cast(int, alpha)));
        float av1 = __builtin_bit_cast(float, __builtin_amdgcn_ds_bpermute(a0 + 4,  __builtin_bit_cast(int, alpha)));
        float av2 = __builtin_bit_cast(float, __builtin_amdgcn_ds_bpermute(a0 + 8,  __builtin_bit_cast(int, alpha)));
        float av3 = __builtin_bit_cast(float, __builtin_amdgcn_ds_bpermute(a0 + 12, __builtin_bit_cast(int, alpha)));
#pragma unroll
        for (int dt = 0; dt < 8; ++dt) {
            o[dt][0] *= av0; o[dt][1] *= av1;
            o[dt][2] *= av2; o[dt][3] *= av3;
        }
    }
    f32x4 acc = {0.f, 0.f, 0.f, 0.f};
#pragma unroll
    for (int ct = 0; ct < 4; ++ct) {
#pragma unroll
        for (int r = 0; r < 4; ++r) s[ct][r] = fexp2(s[ct][r] - m);
        acc += s[ct];
    }
    float rs = (acc[0] + acc[1]) + (acc[2] + acc[3]);
    rs += __shfl_xor(rs, 16);
    rs += __shfl_xor(rs, 32);
    l += rs;
}

__device__ __forceinline__ void p_store(short (&Psw)[16][72], const f32x4 s[4],
                                        int lr, int lg)
{
#pragma unroll
    for (int ct = 0; ct < 4; ++ct)
        *(bfv4*)&Psw[lr][ct * 16 + 4 * lg] = mkfrag(s[ct][0], s[ct][1], s[ct][2], s[ct][3]);
}

__device__ __forceinline__ void pv_dual(const short* __restrict__ Vs,
    const short (&P1)[16][72], const short (&P2)[16][72],
    f32x4 o1[8], f32x4 o2[8], int lr, int lg)
{
    const bfv8 pa0 = *(const bfv8*)&P1[lr][lg * 8];
    const bfv8 pa1 = *(const bfv8*)&P1[lr][32 + lg * 8];
    const bfv8 pb0 = *(const bfv8*)&P2[lr][lg * 8];
    const bfv8 pb1 = *(const bfv8*)&P2[lr][32 + lg * 8];
    const int swz = lr & 7;
#pragma unroll
    for (int dt = 0; dt < 8; ++dt) {
        const int row = dt * 16 + lr;
        const bfv8 bv0 = *(const bfv8*)&Vs[row * 64 + ((lg ^ swz) * 8)];
        const bfv8 bv1 = *(const bfv8*)&Vs[row * 64 + (((4 + lg) ^ swz) * 8)];
        o1[dt] = __builtin_amdgcn_mfma_f32_16x16x32_bf16(pa0, bv0, o1[dt], 0, 0, 0);
        o1[dt] = __builtin_amdgcn_mfma_f32_16x16x32_bf16(pa1, bv1, o1[dt], 0, 0, 0);
        o2[dt] = __builtin_amdgcn_mfma_f32_16x16x32_bf16(pb0, bv0, o2[dt], 0, 0, 0);
        o2[dt] = __builtin_amdgcn_mfma_f32_16x16x32_bf16(pb1, bv1, o2[dt], 0, 0, 0);
    }
}

__device__ __forceinline__ void pv_one(const short* __restrict__ Vs,
    const short (&P2)[16][72], f32x4 o[8], int lr, int lg)
{
    const bfv8 pa0 = *(const bfv8*)&P2[lr][lg * 8];
    const bfv8 pa1 = *(const bfv8*)&P2[lr][32 + lg * 8];
    const int swz = lr & 7;
#pragma unroll
    for (int dt = 0; dt < 8; ++dt) {
        const int row = dt * 16 + lr;
        const bfv8 bv0 = *(const bfv8*)&Vs[row * 64 + ((lg ^ swz) * 8)];
        const bfv8 bv1 = *(const bfv8*)&Vs[row * 64 + (((4 + lg) ^ swz) * 8)];
        o[dt] = __builtin_amdgcn_mfma_f32_16x16x32_bf16(pa0, bv0, o[dt], 0, 0, 0);
        o[dt] = __builtin_amdgcn_mfma_f32_16x16x32_bf16(pa1, bv1, o[dt], 0, 0, 0);
    }
}

// ---------------------------------------------------------------------------
// Split-KV pair-balanced flash attention. Block = (b, h, pair{pi,31-pi},
// split s). Split 0: stream j covers kv [0, hj); split 1: [hj, qtj] where
// hj = ceil((qtj+1)/2). Work ~16-17 units for every block -> 1024 uniform
// blocks (3 resident/CU). Writes unnormalized partials: o bf16 + (m,l) f32.
// ---------------------------------------------------------------------------
__global__ __launch_bounds__(256) void attn_split(
    const short* __restrict__ qg, const short* __restrict__ kg,
    const short* __restrict__ vg,
    short* __restrict__ po0, short* __restrict__ po1,
    float* __restrict__ ml)
{
    __shared__ short Ks[64 * 128];
    __shared__ short Vs[128 * 64];
    __shared__ short Ps1[4][16][72];
    __shared__ short Ps2[4][16][72];

    const int lin = blockIdx.x + 32 * blockIdx.y + 512 * blockIdx.z;
    const int work = (lin & 7) * 128 + (lin >> 3);      // XCD-clustered
    const int s = work & 1;
    const int pi = (work >> 1) & 15;
    const int h = (work >> 5) & 15, b = work >> 9;
    const int qt1 = pi, qt2 = 31 - pi;
    const int h1 = (qt1 + 2) >> 1, h2 = (qt2 + 2) >> 1;
    const int tid = threadIdx.x, w = tid >> 6, lane = tid & 63;
    const int lr = lane & 15, lg = lane >> 4;
    const int a0 = lg * 80;

    const size_t tok0 = ((size_t)b * HH + h) * TT;

    bfv8 aq1[4], aq2[4];
    {
        const size_t q1 = ((size_t)b * TT + qt1 * 64 + w * 16 + lr) * 2048 + h * 128;
        const size_t q2 = ((size_t)b * TT + qt2 * 64 + w * 16 + lr) * 2048 + h * 128;
#pragma unroll
        for (int ks = 0; ks < 4; ++ks) {
            aq1[ks] = *(const bfv8*)&qg[q1 + ks * 32 + lg * 8];
            aq2[ks] = *(const bfv8*)&qg[q2 + ks * 32 + lg * 8];
        }
#pragma unroll
        for (int st = 0; st < 2; ++st) {
            bfv8* aq = st ? aq2 : aq1;
            float ss = 0.f;
#pragma unroll
            for (int ks = 0; ks < 4; ++ks)
#pragma unroll
                for (int j = 0; j < 8; ++j) { float f = bf2f(aq[ks][j]); ss = fmaf(f, f, ss); }
            ss += __shfl_xor(ss, 16);
            ss += __shfl_xor(ss, 32);
            float rr = rsqrtf(ss * (1.0f / 128.0f) + EPSV) * (QSCALE * LOG2E);
#pragma unroll
            for (int ks = 0; ks < 4; ++ks)
#pragma unroll
                for (int j = 0; j < 4; ++j) {
                    unsigned u = cvtpk(bf2f(aq[ks][2 * j]) * rr, bf2f(aq[ks][2 * j + 1]) * rr);
                    aq[ks][2 * j]     = (short)u;
                    aq[ks][2 * j + 1] = (short)(u >> 16);
                }
        }
    }

    f32x4 o1[8] = {}; f32x4 o2[8] = {};
    float m1 = -__builtin_inff(), m2 = -__builtin_inff();
    float l1 = 0.f, l2 = 0.f;

    const size_t vhead = ((size_t)b * HH + h) * (size_t)128 * TT;
    const int krow = tid >> 4, kub = (tid & 15) ^ (krow & 7);
    const int vrow = tid >> 3, vub = (tid & 7) ^ (vrow & 7);
    const int wof = w * 512;

#define STAGE_T(KT)                                                                 \
    {                                                                               \
        const size_t kbase = (tok0 + (KT) * 64) * 128;                              \
        _Pragma("unroll")                                                           \
        for (int p = 0; p < 4; ++p) {                                               \
            gload16(kg + kbase + (p * 16 + krow) * 128 + kub * 8, Ks + wof + p * 2048); \
            gload16(vg + vhead + (size_t)(p * 32 + vrow) * TT + (KT) * 64 + vub * 8,    \
                    Vs + wof + p * 2048);                                           \
        }                                                                           \
    }

#define STEP_DUAL(KT)                                                  \
    {                                                                  \
        f32x4 s1[4], s2[4];                                            \
        qk_dual(Ks, aq1, aq2, s1, s2, lr, lg);                         \
        if ((KT) == qt1) mask_diag(s1, lr, lg, w);                     \
        softmax_lane(s1, m1, l1, o1, a0);                              \
        softmax_lane(s2, m2, l2, o2, a0);                              \
        p_store(Ps1[w], s1, lr, lg);                                   \
        p_store(Ps2[w], s2, lr, lg);                                   \
        pv_dual(Vs, Ps1[w], Ps2[w], o1, o2, lr, lg);                   \
    }
#define STEP_S1(KT)                                                    \
    {                                                                  \
        f32x4 s1[4];                                                   \
        qk_one(Ks, aq1, s1, lr, lg);                                   \
        if ((KT) == qt1) mask_diag(s1, lr, lg, w);                     \
        softmax_lane(s1, m1, l1, o1, a0);                              \
        p_store(Ps1[w], s1, lr, lg);                                   \
        pv_one(Vs, Ps1[w], o1, lr, lg);                                \
    }
#define STEP_S2(KT)                                                    \
    {                                                                  \
        f32x4 s2[4];                                                   \
        qk_one(Ks, aq2, s2, lr, lg);                                   \
        if ((KT) == qt2) mask_diag(s2, lr, lg, w);                     \
        softmax_lane(s2, m2, l2, o2, a0);                              \
        p_store(Ps2[w], s2, lr, lg);                                   \
        pv_one(Vs, Ps2[w], o2, lr, lg);                                \
    }

    if (s == 0) {
        // stream1: kv [0, h1) ; stream2: kv [0, h2).  h1 <= h2.
        for (int kt = 0; kt < h1; ++kt) {
            STAGE_T(kt); __syncthreads();
            STEP_DUAL(kt); __syncthreads();
        }
        for (int kt = h1; kt < h2; ++kt) {
            STAGE_T(kt); __syncthreads();
            STEP_S2(kt); __syncthreads();
        }
    } else {
        // stream1: kv [h1, qt1] ; stream2: kv [h2, qt2].
        const int e1 = (qt1 < h2 - 1) ? qt1 : (h2 - 1);
        for (int kt = h1; kt <= e1; ++kt) {
            STAGE_T(kt); __syncthreads();
            STEP_S1(kt); __syncthreads();
        }
        for (int kt = h2; kt <= qt2; ++kt) {
            STAGE_T(kt); __syncthreads();
            if (kt <= qt1) STEP_DUAL(kt) else STEP_S2(kt);
            __syncthreads();
        }
    }

    // ---- write partials: o (bf16, unnormalized), m/l (f32 per row) ----
    short* po = s ? po1 : po0;
    const int row1 = ((b * HH + h) * TT) + qt1 * 64 + w * 16;
    const int row2 = ((b * HH + h) * TT) + qt2 * 64 + w * 16;
    if (lg == 0) {
        ml[(size_t)(s * 65536 + row1 + lr) * 2]     = m1;
        ml[(size_t)(s * 65536 + row1 + lr) * 2 + 1] = l1;
        ml[(size_t)(s * 65536 + row2 + lr) * 2]     = m2;
        ml[(size_t)(s * 65536 + row2 + lr) * 2 + 1] = l2;
    }
#pragma unroll
    for (int r = 0; r < 4; ++r) {
        const size_t p1 = (size_t)(row1 + 4 * lg + r) * 128 + lr;
        const size_t p2 = (size_t)(row2 + 4 * lg + r) * 128 + lr;
#pragma unroll
        for (int dt = 0; dt < 8; ++dt) {
            po[p1 + dt * 16] = f2bf(o1[dt][r]);
            po[p2 + dt * 16] = f2bf(o2[dt][r]);
        }
    }
}

// ---------------------------------------------------------------------------
// Merge the two KV-split partials into y [4096][2048] bf16.
// One thread = 8 consecutive d of one row. Grid 4096 x 256.
// ---------------------------------------------------------------------------
__global__ __launch_bounds__(256) void attn_merge(
    const short* __restrict__ po0, const short* __restrict__ po1,
    const float* __restrict__ ml, short* __restrict__ y)
{
    const int idx8 = blockIdx.x * 256 + threadIdx.x;
    const int row = idx8 >> 4;
    const int d0 = (idx8 & 15) * 8;
    const float m0 = ml[(size_t)row * 2], l0 = ml[(size_t)row * 2 + 1];
    const float m1 = ml[(size_t)(65536 + row) * 2], l1 = ml[(size_t)(65536 + row) * 2 + 1];
    const float mm = fmaxf(m0, m1);
    const float a0 = exp2f(m0 - mm), a1 = exp2f(m1 - mm);
    const float inv = 1.0f / (l0 * a0 + l1 * a1);
    const float f0 = a0 * inv, f1 = a1 * inv;
    const bfv8 p0 = *(const bfv8*)&po0[(size_t)row * 128 + d0];
    const bfv8 p1 = *(const bfv8*)&po1[(size_t)row * 128 + d0];
    bfv8 r;
#pragma unroll
    for (int j = 0; j < 8; ++j)
        r[j] = f2bf(bf2f(p0[j]) * f0 + bf2f(p1[j]) * f1);
    const int bb = row >> 15, hh = (row >> 11) & 15, t = row & 2047;
    *(bfv8*)&y[(((size_t)bb * TT + t) * 2048) + hh * 128 + d0] = r;
}

// ---------------------------------------------------------------------------
extern "C" void kernel_launch(void* const* d_in, const int* in_sizes, int n_in,
                              void* d_out, int out_size, void* d_ws, size_t ws_size,
                              hipStream_t stream)
{
    const float* x      = (const float*)d_in[0];
    const float* cosb   = (const float*)d_in[1];
    const float* sinb   = (const float*)d_in[2];
    const float* wq_a   = (const float*)d_in[3];
    const float* wq_b   = (const float*)d_in[4];
    const float* wkv_a  = (const float*)d_in[5];
    const float* wk_b   = (const float*)d_in[6];
    const float* wkpe_b = (const float*)d_in[7];
    const float* wv_b   = (const float*)d_in[8];
    const float* wo     = (const float*)d_in[9];

    short* wsp = (short*)d_ws;
    short* W1  = wsp;                 // [2048][2048]  [wq_a^T ; wkv_a^T]
    short* W2  = wsp + 4194304;       // [4096][768]   [wk_b^T ; wv_b^T]
    short* W3  = wsp + 7340032;       // [2048][256]   wkpe_b^T
    short* W4  = wsp + 7864320;       // [2048][1024]  wq_b^T
    short* W5  = wsp + 9961472;       // [2048][2048]  wo^T
    short* C1  = wsp + 14155776;      // [4096][2048]  qlat|kvlat; later y
    short* KC  = wsp + 22544384;      // [4096][2048]  k_content; later PO1
    short* KPE = wsp + 30932992;      // [4096][2048]  k_pe; later qbuf
    short* KB  = wsp + 39321600;      // [b,h,t,d]
    short* VB  = wsp + 47710208;      // [b,h,d,t]
    short* PO0 = wsp;                 // reuses W1..W4 region (free at attn time)
    short* PO1 = KC;                  // reuses KC (free after finalize_k)
    float* ML  = (float*)(wsp + 56098816);
    short* XB  = (short*)d_out;       // x as bf16 (d_out reused as scratch)

    dim3 blk(256);

    TransArgs ta;
    ta.t[0] = {wq_a,   W1,                2048, 1024,    0};
    ta.t[1] = {wkv_a,  W1 + 1024 * 2048,  2048, 1024,  512};
    ta.t[2] = {wk_b,   W2,                 768, 2048, 1024};
    ta.t[3] = {wv_b,   W2 + 2048 * 768,    768, 2048, 1408};
    ta.t[4] = {wkpe_b, W3,                 256, 2048, 1792};
    ta.t[5] = {wq_b,   W4,                1024, 2048, 1920};
    ta.t[6] = {wo,     W5,                2048, 2048, 2432};
    pre_all<<<4096 + 3456, blk, 0, stream>>>(ta, x, XB, 4096);

    // [qlat|kvlat] = x @ [wq_a|wkv_a]
    gemm_bf16<1><<<dim3(16, 32), blk, 0, stream>>>(XB, 2048, W1, 2048, C1, 2048, 2048);
    // k_content = kv_content @ wk_b
    gemm_bf16<1><<<dim3(16, 32), blk, 0, stream>>>(C1 + 1280, 2048, W2, 768, KC, 2048, 768);
    // v = kv_content @ wv_b -> [b,h,d,t]
    gemm_bf16<2><<<dim3(16, 32), blk, 0, stream>>>(C1 + 1280, 2048, W2 + 2048 * 768, 768, VB, 0, 768);
    // k_pe = kv_pe @ wkpe_b
    gemm_bf16<1><<<dim3(16, 32), blk, 0, stream>>>(C1 + 1024, 2048, W3, 256, KPE, 2048, 256);

    finalize_k<<<16384, blk, 0, stream>>>(KC, KPE, cosb, sinb, KB);

    // qbuf = qlat @ wq_b  (into KPE slot; attn rmsnorms on the fly)
    gemm_bf16<1><<<dim3(16, 32), blk, 0, stream>>>(C1, 2048, W4, 1024, KPE, 2048, 1024);

    // split-KV attention -> partials, then merge into C1
    attn_split<<<dim3(32, 16, 2), blk, 0, stream>>>(KPE, KB, VB, PO0, PO1, ML);
    attn_merge<<<4096, blk, 0, stream>>>(PO0, PO1, ML, C1);

    // out = y @ wo
    gemm_bf16<0><<<dim3(16, 32), blk, 0, stream>>>(C1, 2048, W5, 2048, d_out, 2048, 2048);
}